// Round 9
// baseline (222.896 us; speedup 1.0000x reference)
//
#include <hip/hip_runtime.h>

#define B_  4
#define N_  4096
#define H_  16
#define BH_ 64
#define S_  16
#define EPS_ 1e-6f

// kvpart tiles: [64 d][40 n] f16 per tensor (5120 B); double-buffered K+V.
#define NST_ 40
#define TSZ_ 2560                   // f16 per tensor tile
#define KOST_ 72                    // k_out LDS row stride (f16)

typedef _Float16 h2  __attribute__((ext_vector_type(2)));
typedef _Float16 h8  __attribute__((ext_vector_type(8)));
typedef float    f4v __attribute__((ext_vector_type(4)));

struct H2x2 { h2 a, b; };
struct H2x4 { h2 e[4]; };

__device__ __forceinline__ h8 ld_h8(const _Float16* p) {
    f4v r = *(const f4v*)p;                       // ds_read_b128
    return __builtin_bit_cast(h8, r);
}
__device__ __forceinline__ H2x4 ld_h2x4(const _Float16* p) {
    f4v r = *(const f4v*)p;
    return __builtin_bit_cast(H2x4, r);
}
__device__ __forceinline__ void st_h2x2(_Float16* p, h2 a, h2 b) {
    H2x2 t{a, b};
    *(float2*)p = __builtin_bit_cast(float2, t);  // ds_write_b64
}
__device__ __forceinline__ float phi(float x) {
    return x > 0.0f ? x + 1.0f : __expf(x);       // elu(x)+1
}
__device__ __forceinline__ float fdot2(h2 a, h2 b, float c) {
    return __builtin_amdgcn_fdot2(a, b, c, false);
}
__device__ __forceinline__ f4v gload(const void* p) {
    f4v r;
    asm volatile("global_load_dwordx4 %0, %1, off"
                 : "=v"(r) : "v"(p) : "memory");
    return r;
}
#define VMW(N)                                                    \
    do {                                                          \
        asm volatile("s_waitcnt vmcnt(" #N ")" ::: "memory");     \
        __builtin_amdgcn_sched_barrier(0);                        \
    } while (0)

// ---------------------------------------------------------------------------
// Kernel 1a v10 — OCCUPANCY restructure. 8 rounds showed per-wave streaming
// rate is ~fixed and every variant ran 1 block/CU, <=4 waves/CU (Occupancy
// 8-32%) -> chip plateaus at ~1.5 TB/s invariant to everything else. Fix:
// 4 blocks/CU. Block = one (b,h,s): 256 rows, 8 chunks x 32 rows; LDS only
// 20.5 KB (double-buffered [64][40] K+V); ~100 VGPR; plain __syncthreads
// double-buffer (m97 pattern — cross-block overlap absorbs the drain).
// grid (16 s, 16 h, 4 b) = 1024 blocks, 256 thr.
// ---------------------------------------------------------------------------
__global__ __launch_bounds__(256, 4) void k_kvpart(const float* __restrict__ K,
                                                   const float* __restrict__ V,
                                                   float* __restrict__ kvpart,
                                                   float* __restrict__ kspart) {
    const int s = blockIdx.x, h = blockIdx.y, b = blockIdx.z;
    const int t = threadIdx.x, wv = t >> 6, lane = t & 63;
    const int rp2 = t >> 4, c4 = t & 15;      // 16 row-groups x 16 d-quads
    const int l15 = lane & 15;

    __shared__ __align__(16) _Float16 pool[2 * 2 * TSZ_];   // 20480 B

    f4v k0r, k1r, v0r, v1r;
    const float* baseK = K + ((size_t)(b * N_ + s * 256) * 1024 + h * 64 + c4 * 4);
    const float* baseV = V + ((size_t)(b * N_ + s * 256) * 1024 + h * 64 + c4 * 4);

    auto LOADX = [&](int chunk) {             // 2 rows x f4 per tensor
        const int ro = (chunk * 32 + 2 * rp2) * 1024;
        k0r = *(const f4v*)(baseK + ro);
        k1r = *(const f4v*)(baseK + ro + 1024);
        v0r = *(const f4v*)(baseV + ro);
        v1r = *(const f4v*)(baseV + ro + 1024);
    };
    auto STOREX = [&](int bf) {
        _Float16* Kt = pool + bf * (2 * TSZ_);
        _Float16* Vt = Kt + TSZ_;
        const int nn = 2 * rp2;
#pragma unroll
        for (int dj = 0; dj < 4; ++dj) {
            const int d = 4 * c4 + dj;
            h2 kk, vv;
            kk.x = (_Float16)phi(k0r[dj]); kk.y = (_Float16)phi(k1r[dj]);
            vv.x = (_Float16)v0r[dj];      vv.y = (_Float16)v1r[dj];
            *(h2*)&Kt[d * NST_ + nn] = kk;   // ds_write_b32
            *(h2*)&Vt[d * NST_ + nn] = vv;
        }
    };

    f4v acc[4];                               // wave's 16d x 64m output strip
#pragma unroll
    for (int j = 0; j < 4; ++j) acc[j] = (f4v){0.f, 0.f, 0.f, 0.f};
    float ksum = 0.f;
    h2 one2; one2.x = (_Float16)1.0f; one2.y = (_Float16)1.0f;
    const int fo = (lane >> 4) * 8;

    auto COMPUTE = [&](int bf) {
        const _Float16* Kt = pool + bf * (2 * TSZ_);
        const _Float16* Vt = Kt + TSZ_;
        h8 a0 = ld_h8(&Kt[(16 * wv + l15) * NST_ + fo]);
#pragma unroll
        for (int j = 0; j < 4; ++j) {
            h8 b0 = ld_h8(&Vt[(16 * j + l15) * NST_ + fo]);
            acc[j] = __builtin_amdgcn_mfma_f32_16x16x32_f16(a0, b0, acc[j], 0, 0, 0);
        }
        if (wv == 0) {                        // ksum: lane owns d = lane
#pragma unroll
            for (int q = 0; q < 4; ++q) {
                H2x4 x = ld_h2x4(&Kt[lane * NST_ + q * 8]);
#pragma unroll
                for (int i = 0; i < 4; ++i) ksum = fdot2(x.e[i], one2, ksum);
            }
        }
    };

    LOADX(0);
    STOREX(0);
    __syncthreads();
#pragma unroll
    for (int c = 0; c < 8; ++c) {
        if (c < 7) LOADX(c + 1);
        COMPUTE(c & 1);
        if (c < 7) {
            STOREX((c + 1) & 1);              // other buffer — no race w/ compute
            __syncthreads();
        }
    }

    // epilogue (C layout: col=lane&15 -> m, row=(lane>>4)*4+r -> local d; m89)
    const int bh = b * 16 + h;
    float* outp = kvpart + (size_t)(bh * S_ + s) * 4096;
#pragma unroll
    for (int j = 0; j < 4; ++j)
#pragma unroll
        for (int r = 0; r < 4; ++r) {
            const int d = 16 * wv + (lane >> 4) * 4 + r;
            const int m = 16 * j + l15;
            outp[d * 64 + m] = acc[j][r];
        }
    if (wv == 0) kspart[(size_t)(bh * S_ + s) * 64 + lane] = ksum;
}

// ---------------------------------------------------------------------------
// Kernel 1b: reduce partials -> KV, Ksum; Mt[j][d] = sum KV[d][m]*W[j][..].
// Unchanged (passing).
// ---------------------------------------------------------------------------
__global__ __launch_bounds__(256, 2) void k_makeM(const float* __restrict__ kvpart,
                                                  const float* __restrict__ kspart,
                                                  const float* __restrict__ W,
                                                  _Float16* __restrict__ Mt,
                                                  float* __restrict__ Ksum) {
    const int bh = blockIdx.x, dq = blockIdx.y;
    const int h  = bh & 15;
    const int t  = threadIdx.x;

    __shared__ float KVs[16][68];
    __shared__ float Ws[64][68];

    const f4v* W4  = (const f4v*)W;

    f4v rr[S_];
    {
        const int row = t >> 4, c4 = t & 15;
        const float* g = kvpart + ((size_t)(bh * S_) * 4096 +
                                   (dq * 16 + row) * 64 + c4 * 4);
#pragma unroll
        for (int s = 0; s < S_; ++s) rr[s] = gload(g + (size_t)s * 4096);
    }
    for (int idx = t; idx < 1024; idx += 256) {
        int wrow = idx >> 4, wc = idx & 15;
        *(f4v*)&Ws[wrow][wc * 4] = W4[(size_t)wrow * 256 + h * 16 + wc];
    }
    if (dq == 0 && t < 64) {
        float ks = 0.f;
#pragma unroll
        for (int s = 0; s < S_; ++s) ks += kspart[(size_t)(bh * S_ + s) * 64 + t];
        Ksum[(size_t)bh * 64 + t] = ks;
    }
    VMW(0);
    {
        const int row = t >> 4, c4 = t & 15;
        f4v r = {0.f, 0.f, 0.f, 0.f};
#pragma unroll
        for (int s = 0; s < S_; ++s) r += rr[s];
        *(f4v*)&KVs[row][c4 * 4] = r;
    }
    __syncthreads();

    const int j = t >> 2, dl = (t & 3) * 4;
    float acc[4] = {0.f, 0.f, 0.f, 0.f};
#pragma unroll 4
    for (int m4 = 0; m4 < 16; ++m4) {
        f4v wr  = *(const f4v*)&Ws[j][m4 * 4];
        f4v kv0 = *(const f4v*)&KVs[dl + 0][m4 * 4];
        f4v kv1 = *(const f4v*)&KVs[dl + 1][m4 * 4];
        f4v kv2 = *(const f4v*)&KVs[dl + 2][m4 * 4];
        f4v kv3 = *(const f4v*)&KVs[dl + 3][m4 * 4];
        acc[0] += wr[0] * kv0[0] + wr[1] * kv0[1] + wr[2] * kv0[2] + wr[3] * kv0[3];
        acc[1] += wr[0] * kv1[0] + wr[1] * kv1[1] + wr[2] * kv1[2] + wr[3] * kv1[3];
        acc[2] += wr[0] * kv2[0] + wr[1] * kv2[1] + wr[2] * kv2[2] + wr[3] * kv2[3];
        acc[3] += wr[0] * kv3[0] + wr[1] * kv3[1] + wr[2] * kv3[2] + wr[3] * kv3[3];
    }
    h2 lo, hi;
    lo.x = (_Float16)acc[0]; lo.y = (_Float16)acc[1];
    hi.x = (_Float16)acc[2]; hi.y = (_Float16)acc[3];
    H2x2 pk{lo, hi};
    *(float2*)&Mt[((size_t)bh * 64 + j) * 64 + dq * 16 + dl] =
        __builtin_bit_cast(float2, pk);
}

// ---------------------------------------------------------------------------
// Kernel 2 v10 — same occupancy fix. Block = 16 n-rows (was 64): grid
// (256 nc, 4 b) = 1024 blocks, LDS 23 KB, tiny VGPR. Wave = one 16-j tile.
// Loops all 16 heads, accumulates, writes bias + sum directly (k_red fused).
// ---------------------------------------------------------------------------
__global__ __launch_bounds__(256, 4) void k_out(const float* __restrict__ Q,
                                                const _Float16* __restrict__ Mtg,
                                                const float* __restrict__ Ksum,
                                                const float* __restrict__ bout,
                                                float* __restrict__ out) {
    const int nc = blockIdx.x, b = blockIdx.y;
    const int n0 = nc * 16;
    const int t = threadIdx.x, wv = t >> 6, lane = t & 63;
    const int rp16 = t >> 4, c4 = t & 15, l15 = lane & 15;

    // per buffer: Qp[16][72] + Mt[64][72]
    __shared__ __align__(16) _Float16 pool[2 * 80 * KOST_];   // 23040 B
    __shared__ float zz[16];
    __shared__ h2 Kss[2][32];

    f4v qr, mr0, mr1;
    float ksa = 0.f, ksb = 0.f;
    auto LOAD = [&](int hh) {
        const int bh = b * 16 + hh;
        qr = *(const f4v*)(Q + ((size_t)(b * N_ + n0 + rp16) * 1024 + hh * 64 + c4 * 4));
        const f4v* gm = (const f4v*)(Mtg + (size_t)bh * 4096);
        mr0 = gm[t];
        mr1 = gm[t + 256];
        if (t < 32) {
            ksa = Ksum[(size_t)bh * 64 + 2 * t];
            ksb = Ksum[(size_t)bh * 64 + 2 * t + 1];
        }
    };
    auto STORE = [&](int bf) {
        _Float16* Qp = pool + bf * (80 * KOST_);
        _Float16* Mt = Qp + 16 * KOST_;
        h2 p0, p1;
        p0.x = (_Float16)phi(qr[0]); p0.y = (_Float16)phi(qr[1]);
        p1.x = (_Float16)phi(qr[2]); p1.y = (_Float16)phi(qr[3]);
        st_h2x2(&Qp[rp16 * KOST_ + 4 * c4], p0, p1);
        *(f4v*)&Mt[(t >> 3) * KOST_ + (t & 7) * 8] = mr0;
        *(f4v*)&Mt[((t + 256) >> 3) * KOST_ + (t & 7) * 8] = mr1;
        if (t < 32) { h2 kk; kk.x = (_Float16)ksa; kk.y = (_Float16)ksb; Kss[bf][t] = kk; }
    };

    const int fo = (lane >> 4) * 8;
    float facc[4] = {0.f, 0.f, 0.f, 0.f};

    LOAD(0);
    STORE(0);

    for (int hh = 0; hh < 16; ++hh) {
        if (hh + 1 < 16) LOAD(hh + 1);
        __syncthreads();                      // buf ready / prev MFMA done
        const int bf = hh & 1;
        const _Float16* Qp = pool + bf * (80 * KOST_);
        const _Float16* Mt = Qp + 16 * KOST_;

        if (t < 16) {                         // z-denominator for row t
            float zp = 0.f;
#pragma unroll
            for (int c = 0; c < 8; ++c) {
                H2x4 x = ld_h2x4(&Qp[t * KOST_ + c * 8]);
#pragma unroll
                for (int i = 0; i < 4; ++i) zp = fdot2(x.e[i], Kss[bf][c * 4 + i], zp);
            }
            zz[t] = 1.0f / (zp + EPS_);
        }
        __syncthreads();

        f4v acc = (f4v){0.f, 0.f, 0.f, 0.f};
#pragma unroll
        for (int ks = 0; ks < 2; ++ks) {
            h8 a0 = ld_h8(&Qp[l15 * KOST_ + ks * 32 + fo]);
            h8 b0 = ld_h8(&Mt[(16 * wv + l15) * KOST_ + ks * 32 + fo]);
            acc = __builtin_amdgcn_mfma_f32_16x16x32_f16(a0, b0, acc, 0, 0, 0);
        }
#pragma unroll
        for (int r = 0; r < 4; ++r) {
            const int row = (lane >> 4) * 4 + r;
            facc[r] += zz[row] * acc[r];
        }
        if (hh + 1 < 16) STORE((hh + 1) & 1); // other buffer
    }

    const int j = 16 * wv + l15;
    const float bj = bout[j];
#pragma unroll
    for (int r = 0; r < 4; ++r) {
        const int n = n0 + (lane >> 4) * 4 + r;
        out[(size_t)(b * N_ + n) * 64 + j] = bj + facc[r];
    }
}

// ---------------------------------------------------------------------------
extern "C" void kernel_launch(void* const* d_in, const int* in_sizes, int n_in,
                              void* d_out, int out_size, void* d_ws, size_t ws_size,
                              hipStream_t stream) {
    const float* q  = (const float*)d_in[0];
    const float* k  = (const float*)d_in[1];
    const float* v  = (const float*)d_in[2];
    const float* W  = (const float*)d_in[3];
    const float* bo = (const float*)d_in[4];
    float* out = (float*)d_out;

    float* ws      = (float*)d_ws;
    float* kvpart  = ws;                                    // 64*16*4096 = 16 MB
    float* kspart  = kvpart + (size_t)BH_ * S_ * 4096;      // 256 KB
    float* Mt      = kspart + (size_t)BH_ * S_ * 64;        // 64*4096 f16 = 512 KB
    float* Ksum    = Mt + (size_t)BH_ * 4096 / 2;           // 16 KB

    k_kvpart<<<dim3(S_, H_, B_), 256, 0, stream>>>(k, v, kvpart, kspart);
    k_makeM<<<dim3(BH_, 4), 256, 0, stream>>>(kvpart, kspart, W, (_Float16*)Mt, Ksum);
    k_out<<<dim3(N_ / 16, B_), 256, 0, stream>>>(q, (const _Float16*)Mt, Ksum, bo, out);
}

// Round 11
// 220.820 us; speedup vs baseline: 1.0094x; 1.0094x over previous
//
#include <hip/hip_runtime.h>

#define B_  4
#define N_  4096
#define H_  16
#define BH_ 64
#define S_  16
#define EPS_ 1e-6f

// kvpart tiles: [64 d][40 n] f16 per tensor (5120 B); double-buffered K+V.
#define NST_ 40
#define TSZ_ 2560                   // f16 per tensor tile
#define KOST_ 72                    // k_out LDS row stride (f16)

typedef _Float16 h2  __attribute__((ext_vector_type(2)));
typedef _Float16 h8  __attribute__((ext_vector_type(8)));
typedef float    f4v __attribute__((ext_vector_type(4)));

struct H2x2 { h2 a, b; };
struct H2x4 { h2 e[4]; };

__device__ __forceinline__ h8 ld_h8(const _Float16* p) {
    f4v r = *(const f4v*)p;                       // ds_read_b128
    return __builtin_bit_cast(h8, r);
}
__device__ __forceinline__ H2x4 ld_h2x4(const _Float16* p) {
    f4v r = *(const f4v*)p;
    return __builtin_bit_cast(H2x4, r);
}
__device__ __forceinline__ void st_h2x2(_Float16* p, h2 a, h2 b) {
    H2x2 t{a, b};
    *(float2*)p = __builtin_bit_cast(float2, t);  // ds_write_b64
}
__device__ __forceinline__ float phi(float x) {
    return x > 0.0f ? x + 1.0f : __expf(x);       // elu(x)+1
}
__device__ __forceinline__ float fdot2(h2 a, h2 b, float c) {
    return __builtin_amdgcn_fdot2(a, b, c, false);
}

// ---------------------------------------------------------------------------
// Kernel 0: zero the atomic accumulators (workspace is re-poisoned per run).
// KV (64*4096 f32) + Ksum (64*64 f32) = 266240 floats = 1040 x 256.
// ---------------------------------------------------------------------------
__global__ __launch_bounds__(256) void k_zero(float* __restrict__ p) {
    p[(size_t)blockIdx.x * 256 + threadIdx.x] = 0.f;
}

// ---------------------------------------------------------------------------
// Kernel 1a v12: identical to v11 (v10 compute structure + atomic epilogue).
// grid (16 s, 16 h, 4 b) = 1024 blocks, 256 thr, 4 blocks/CU.
// ---------------------------------------------------------------------------
__global__ __launch_bounds__(256, 4) void k_kvpart(const float* __restrict__ K,
                                                   const float* __restrict__ V,
                                                   float* __restrict__ KV,
                                                   float* __restrict__ Ksum) {
    const int s = blockIdx.x, h = blockIdx.y, b = blockIdx.z;
    const int t = threadIdx.x, wv = t >> 6, lane = t & 63;
    const int rp2 = t >> 4, c4 = t & 15;      // 16 row-groups x 16 d-quads
    const int l15 = lane & 15;

    __shared__ __align__(16) _Float16 pool[2 * 2 * TSZ_];   // 20480 B

    f4v k0r, k1r, v0r, v1r;
    const float* baseK = K + ((size_t)(b * N_ + s * 256) * 1024 + h * 64 + c4 * 4);
    const float* baseV = V + ((size_t)(b * N_ + s * 256) * 1024 + h * 64 + c4 * 4);

    auto LOADX = [&](int chunk) {             // 2 rows x f4 per tensor
        const int ro = (chunk * 32 + 2 * rp2) * 1024;
        k0r = *(const f4v*)(baseK + ro);
        k1r = *(const f4v*)(baseK + ro + 1024);
        v0r = *(const f4v*)(baseV + ro);
        v1r = *(const f4v*)(baseV + ro + 1024);
    };
    auto STOREX = [&](int bf) {
        _Float16* Kt = pool + bf * (2 * TSZ_);
        _Float16* Vt = Kt + TSZ_;
        const int nn = 2 * rp2;
#pragma unroll
        for (int dj = 0; dj < 4; ++dj) {
            const int d = 4 * c4 + dj;
            h2 kk, vv;
            kk.x = (_Float16)phi(k0r[dj]); kk.y = (_Float16)phi(k1r[dj]);
            vv.x = (_Float16)v0r[dj];      vv.y = (_Float16)v1r[dj];
            *(h2*)&Kt[d * NST_ + nn] = kk;   // ds_write_b32
            *(h2*)&Vt[d * NST_ + nn] = vv;
        }
    };

    f4v acc[4];                               // wave's 16d x 64m output strip
#pragma unroll
    for (int j = 0; j < 4; ++j) acc[j] = (f4v){0.f, 0.f, 0.f, 0.f};
    float ksum = 0.f;
    h2 one2; one2.x = (_Float16)1.0f; one2.y = (_Float16)1.0f;
    const int fo = (lane >> 4) * 8;

    auto COMPUTE = [&](int bf) {
        const _Float16* Kt = pool + bf * (2 * TSZ_);
        const _Float16* Vt = Kt + TSZ_;
        h8 a0 = ld_h8(&Kt[(16 * wv + l15) * NST_ + fo]);
#pragma unroll
        for (int j = 0; j < 4; ++j) {
            h8 b0 = ld_h8(&Vt[(16 * j + l15) * NST_ + fo]);
            acc[j] = __builtin_amdgcn_mfma_f32_16x16x32_f16(a0, b0, acc[j], 0, 0, 0);
        }
        if (wv == 0) {                        // ksum: lane owns d = lane
#pragma unroll
            for (int q = 0; q < 4; ++q) {
                H2x4 x = ld_h2x4(&Kt[lane * NST_ + q * 8]);
#pragma unroll
                for (int i = 0; i < 4; ++i) ksum = fdot2(x.e[i], one2, ksum);
            }
        }
    };

    LOADX(0);
    STOREX(0);
    __syncthreads();
#pragma unroll
    for (int c = 0; c < 8; ++c) {
        if (c < 7) LOADX(c + 1);
        COMPUTE(c & 1);
        if (c < 7) {
            STOREX((c + 1) & 1);              // other buffer — no race w/ compute
            __syncthreads();
        }
    }

    // epilogue: atomic accumulate the (bh,s)-tile into final KV/Ksum
    // (C layout: col=lane&15 -> m, row=(lane>>4)*4+r -> local d; m89)
    const int bh = b * 16 + h;
    float* outp = KV + (size_t)bh * 4096;
#pragma unroll
    for (int j = 0; j < 4; ++j)
#pragma unroll
        for (int r = 0; r < 4; ++r) {
            const int d = 16 * wv + (lane >> 4) * 4 + r;
            const int m = 16 * j + l15;
            atomicAdd(&outp[d * 64 + m], acc[j][r]);
        }
    if (wv == 0) atomicAdd(&Ksum[(size_t)bh * 64 + lane], ksum);
}

// ---------------------------------------------------------------------------
// Kernel 1b v12: Mt[j][d] = sum_m KV[d][m] * W[j][h*64+m], f16 transposed.
// FIX of v11's coverage bug: restore grid (BH_, 4) with dq = blockIdx.y —
// each block covers ONE 16-row d-quarter (v11 ran 64 blocks but kept the
// quarter-sized thread map, leaving d=16..63 of Mt unwritten -> absmax 3.9e-2).
// Structure = v10's passing makeM minus the s-reduction (KV already final).
// ---------------------------------------------------------------------------
__global__ __launch_bounds__(256, 4) void k_makeM(const float* __restrict__ KV,
                                                  const float* __restrict__ W,
                                                  _Float16* __restrict__ Mt) {
    const int bh = blockIdx.x, dq = blockIdx.y;
    const int h  = bh & 15;
    const int t  = threadIdx.x;

    __shared__ float KVs[16][68];   // KVs[d - dq*16][m]
    __shared__ float Ws[64][68];    // Ws[j][m]

    const f4v* kv4 = (const f4v*)KV;
    const f4v* W4  = (const f4v*)W;

    {   // stage the 16-row d-slice of final KV: one f4v per thread
        const int row = t >> 4, c4 = t & 15;
        *(f4v*)&KVs[row][c4 * 4] = kv4[(size_t)bh * 1024 + (dq * 16 + row) * 16 + c4];
    }
    for (int idx = t; idx < 1024; idx += 256) {
        const int wrow = idx >> 4, wc = idx & 15;
        *(f4v*)&Ws[wrow][wc * 4] = W4[(size_t)wrow * 256 + h * 16 + wc];
    }
    __syncthreads();

    // thread -> output j = t>>2 (all 64 j), 4 d's at dl = (t&3)*4
    const int j = t >> 2, dl = (t & 3) * 4;
    float acc[4] = {0.f, 0.f, 0.f, 0.f};
#pragma unroll 4
    for (int m4 = 0; m4 < 16; ++m4) {
        f4v wr  = *(const f4v*)&Ws[j][m4 * 4];
        f4v kv0 = *(const f4v*)&KVs[dl + 0][m4 * 4];
        f4v kv1 = *(const f4v*)&KVs[dl + 1][m4 * 4];
        f4v kv2 = *(const f4v*)&KVs[dl + 2][m4 * 4];
        f4v kv3 = *(const f4v*)&KVs[dl + 3][m4 * 4];
        acc[0] += wr[0] * kv0[0] + wr[1] * kv0[1] + wr[2] * kv0[2] + wr[3] * kv0[3];
        acc[1] += wr[0] * kv1[0] + wr[1] * kv1[1] + wr[2] * kv1[2] + wr[3] * kv1[3];
        acc[2] += wr[0] * kv2[0] + wr[1] * kv2[1] + wr[2] * kv2[2] + wr[3] * kv2[3];
        acc[3] += wr[0] * kv3[0] + wr[1] * kv3[1] + wr[2] * kv3[2] + wr[3] * kv3[3];
    }
    h2 lo, hi;
    lo.x = (_Float16)acc[0]; lo.y = (_Float16)acc[1];
    hi.x = (_Float16)acc[2]; hi.y = (_Float16)acc[3];
    H2x2 pk{lo, hi};
    *(float2*)&Mt[((size_t)bh * 64 + j) * 64 + dq * 16 + dl] =
        __builtin_bit_cast(float2, pk);
}

// ---------------------------------------------------------------------------
// Kernel 2: UNCHANGED from passing v10 (fused out+red). Block = 16 n-rows,
// grid (256 nc, 4 b) = 1024 blocks; loops 16 heads; writes bias + sum.
// ---------------------------------------------------------------------------
__global__ __launch_bounds__(256, 4) void k_out(const float* __restrict__ Q,
                                                const _Float16* __restrict__ Mtg,
                                                const float* __restrict__ Ksum,
                                                const float* __restrict__ bout,
                                                float* __restrict__ out) {
    const int nc = blockIdx.x, b = blockIdx.y;
    const int n0 = nc * 16;
    const int t = threadIdx.x, wv = t >> 6, lane = t & 63;
    const int rp16 = t >> 4, c4 = t & 15, l15 = lane & 15;

    // per buffer: Qp[16][72] + Mt[64][72]
    __shared__ __align__(16) _Float16 pool[2 * 80 * KOST_];   // 23040 B
    __shared__ float zz[16];
    __shared__ h2 Kss[2][32];

    f4v qr, mr0, mr1;
    float ksa = 0.f, ksb = 0.f;
    auto LOAD = [&](int hh) {
        const int bh = b * 16 + hh;
        qr = *(const f4v*)(Q + ((size_t)(b * N_ + n0 + rp16) * 1024 + hh * 64 + c4 * 4));
        const f4v* gm = (const f4v*)(Mtg + (size_t)bh * 4096);
        mr0 = gm[t];
        mr1 = gm[t + 256];
        if (t < 32) {
            ksa = Ksum[(size_t)bh * 64 + 2 * t];
            ksb = Ksum[(size_t)bh * 64 + 2 * t + 1];
        }
    };
    auto STORE = [&](int bf) {
        _Float16* Qp = pool + bf * (80 * KOST_);
        _Float16* Mt = Qp + 16 * KOST_;
        h2 p0, p1;
        p0.x = (_Float16)phi(qr[0]); p0.y = (_Float16)phi(qr[1]);
        p1.x = (_Float16)phi(qr[2]); p1.y = (_Float16)phi(qr[3]);
        st_h2x2(&Qp[rp16 * KOST_ + 4 * c4], p0, p1);
        *(f4v*)&Mt[(t >> 3) * KOST_ + (t & 7) * 8] = mr0;
        *(f4v*)&Mt[((t + 256) >> 3) * KOST_ + (t & 7) * 8] = mr1;
        if (t < 32) { h2 kk; kk.x = (_Float16)ksa; kk.y = (_Float16)ksb; Kss[bf][t] = kk; }
    };

    const int fo = (lane >> 4) * 8;
    float facc[4] = {0.f, 0.f, 0.f, 0.f};

    LOAD(0);
    STORE(0);

    for (int hh = 0; hh < 16; ++hh) {
        if (hh + 1 < 16) LOAD(hh + 1);
        __syncthreads();                      // buf ready / prev MFMA done
        const int bf = hh & 1;
        const _Float16* Qp = pool + bf * (80 * KOST_);
        const _Float16* Mt = Qp + 16 * KOST_;

        if (t < 16) {                         // z-denominator for row t
            float zp = 0.f;
#pragma unroll
            for (int c = 0; c < 8; ++c) {
                H2x4 x = ld_h2x4(&Qp[t * KOST_ + c * 8]);
#pragma unroll
                for (int i = 0; i < 4; ++i) zp = fdot2(x.e[i], Kss[bf][c * 4 + i], zp);
            }
            zz[t] = 1.0f / (zp + EPS_);
        }
        __syncthreads();

        f4v acc = (f4v){0.f, 0.f, 0.f, 0.f};
#pragma unroll
        for (int ks = 0; ks < 2; ++ks) {
            h8 a0 = ld_h8(&Qp[l15 * KOST_ + ks * 32 + fo]);
            h8 b0 = ld_h8(&Mt[(16 * wv + l15) * KOST_ + ks * 32 + fo]);
            acc = __builtin_amdgcn_mfma_f32_16x16x32_f16(a0, b0, acc, 0, 0, 0);
        }
#pragma unroll
        for (int r = 0; r < 4; ++r) {
            const int row = (lane >> 4) * 4 + r;
            facc[r] += zz[row] * acc[r];
        }
        if (hh + 1 < 16) STORE((hh + 1) & 1); // other buffer
    }

    const int j = 16 * wv + l15;
    const float bj = bout[j];
#pragma unroll
    for (int r = 0; r < 4; ++r) {
        const int n = n0 + (lane >> 4) * 4 + r;
        out[(size_t)(b * N_ + n) * 64 + j] = bj + facc[r];
    }
}

// ---------------------------------------------------------------------------
extern "C" void kernel_launch(void* const* d_in, const int* in_sizes, int n_in,
                              void* d_out, int out_size, void* d_ws, size_t ws_size,
                              hipStream_t stream) {
    const float* q  = (const float*)d_in[0];
    const float* k  = (const float*)d_in[1];
    const float* v  = (const float*)d_in[2];
    const float* W  = (const float*)d_in[3];
    const float* bo = (const float*)d_in[4];
    float* out = (float*)d_out;

    float* ws   = (float*)d_ws;
    float* KV   = ws;                          // 64*4096 f32 = 1 MB
    float* Ksum = KV + (size_t)BH_ * 4096;     // 64*64 f32 = 16 KB
    float* Mt   = Ksum + (size_t)BH_ * 64;     // 64*4096 f16 = 512 KB

    k_zero<<<1040, 256, 0, stream>>>(KV);      // zeroes KV + Ksum (contiguous)
    k_kvpart<<<dim3(S_, H_, B_), 256, 0, stream>>>(k, v, KV, Ksum);
    k_makeM<<<dim3(BH_, 4), 256, 0, stream>>>(KV, W, (_Float16*)Mt);
    k_out<<<dim3(N_ / 16, B_), 256, 0, stream>>>(q, (const _Float16*)Mt, Ksum, bo, out);
}